// Round 1
// baseline (2115.924 us; speedup 1.0000x reference)
//
#include <hip/hip_runtime.h>

#define D_   32
#define H_   256
#define W_   256
#define HW_  (H_ * W_)
#define DHW_ (D_ * H_ * W_)   // 2097152
#define V_   40000
#define CIN  16
#define COUT 32
#define P_   32
#define EPS_ 1e-5f
#define NVOX 64               // voxels per block in scatter kernel

// ---------- K1: feats[v][c] = mean over P of voxels[v][c][:] ----------
__global__ void feats_kernel(const float* __restrict__ vox, float* __restrict__ feats) {
    int idx = blockIdx.x * 256 + threadIdx.x;      // one thread per (v,c)
    if (idx >= V_ * CIN) return;
    const float4* p = (const float4*)(vox + (size_t)idx * P_);
    float s = 0.f;
#pragma unroll
    for (int j = 0; j < P_ / 4; ++j) {
        float4 q = p[j];
        s += q.x + q.y + q.z + q.w;
    }
    feats[idx] = s * (1.0f / (float)P_);
}

// ---------- K2: fill d_out with bias (pre-norm init) + zero stats ----------
__global__ void fill_kernel(float* __restrict__ out, const float* __restrict__ bias,
                            float* __restrict__ stats) {
    if (blockIdx.x == 0 && threadIdx.x < 2 * COUT) stats[threadIdx.x] = 0.f;
    int idx4 = blockIdx.x * 256 + threadIdx.x;     // over float4 elements
    const int n4 = COUT * DHW_ / 4;
    if (idx4 >= n4) return;
    int c = idx4 / (DHW_ / 4);
    float b = bias[c];
    ((float4*)out)[idx4] = make_float4(b, b, b, b);
}

// ---------- K3: scatter conv contributions + on-the-fly BN stats ----------
// threads: 256 = 32 out-channels (o) x 8 voxel slots. Full lane utilization.
__global__ void __launch_bounds__(256) scatter_conv_kernel(
    const float* __restrict__ feats, const int* __restrict__ indices,
    const float* __restrict__ conv_w, float* __restrict__ out,
    float* __restrict__ stats)
{
    __shared__ float ws_[27 * CIN * COUT];   // [k][i][o] layout -> conflict-free
    __shared__ float f_[NVOX][CIN];
    __shared__ int4  pos_[NVOX];
    __shared__ float lsum[COUT], lsq[COUT];

    int t = threadIdx.x;
    // stage weights, transposed (o,i,k) -> [k][i][o]; reads are coalesced
    for (int j = t; j < 27 * CIN * COUT; j += 256) {
        int k = j % 27; int i = (j / 27) % CIN; int o = j / (27 * CIN);
        ws_[(k * CIN + i) * COUT + o] = conv_w[j];
    }
    int vbase = blockIdx.x * NVOX;
    for (int j = t; j < NVOX * CIN; j += 256) {
        int slot = j / CIN; int i = j % CIN;
        int v = vbase + slot;
        f_[slot][i] = (v < V_) ? feats[v * CIN + i] : 0.f;
    }
    if (t < NVOX) {
        int v = vbase + t;
        int4 p = make_int4(0, 0, 0, 0);
        if (v < V_) {
            int w = indices[v * 3 + 0], h = indices[v * 3 + 1], d = indices[v * 3 + 2];
            int valid = (w >= 0 && w < W_ && h >= 0 && h < H_ && d >= 0 && d < D_) ? 1 : 0;
            p = make_int4(w, h, d, valid);
        }
        pos_[t] = p;
    }
    if (t < COUT) { lsum[t] = 0.f; lsq[t] = 0.f; }
    __syncthreads();

    int o = t % COUT;
    int slot0 = t / COUT;   // 0..7
    float dsum = 0.f, dsq = 0.f;

    for (int vv = slot0; vv < NVOX; vv += 8) {
        int4 p = pos_[vv];
        if (!p.w) continue;
        float fr[CIN];
#pragma unroll
        for (int i = 0; i < CIN; ++i) fr[i] = f_[vv][i];   // LDS broadcast
        for (int k = 0; k < 27; ++k) {
            int kz = k / 9, ky = (k / 3) % 3, kx = k % 3;
            // cross-correlation: out[q] += w[k] * in[q + k - 1]  =>  q = p + 1 - k
            int dq = p.z + 1 - kz, hq = p.y + 1 - ky, wq = p.x + 1 - kx;
            if ((unsigned)dq < D_ && (unsigned)hq < H_ && (unsigned)wq < W_) {
                const float* wk = &ws_[k * CIN * COUT + o];
                float acc = 0.f;
#pragma unroll
                for (int i = 0; i < CIN; ++i) acc += wk[i * COUT] * fr[i];
                size_t oidx = (size_t)o * DHW_ + (size_t)dq * HW_ + (size_t)hq * W_ + wq;
                float old = atomicAdd(&out[oidx], acc);
                dsum += acc;
                dsq  += acc * (2.f * old + acc);   // exact sum-of-squares delta
            }
        }
    }
    atomicAdd(&lsum[o], dsum);
    atomicAdd(&lsq[o], dsq);
    __syncthreads();
    if (t < COUT) {
        atomicAdd(&stats[t], lsum[t]);
        atomicAdd(&stats[t + COUT], lsq[t]);
    }
}

// ---------- K4: finalize per-channel mean / inv_std ----------
__global__ void finalize_kernel(const float* __restrict__ stats,
                                const float* __restrict__ bias,
                                float* __restrict__ mi) {
    int t = threadIdx.x;
    if (t < COUT) {
        float b = bias[t];
        float n = (float)DHW_;
        float mean = b + stats[t] / n;
        float ex2  = b * b + stats[t + COUT] / n;
        float var  = fmaxf(ex2 - mean * mean, 0.f);
        mi[t] = mean;
        mi[t + COUT] = 1.0f / sqrtf(var + EPS_);
    }
}

// ---------- K5: normalize + affine + ReLU in place ----------
__global__ void norm_kernel(float* __restrict__ out, const float* __restrict__ mi,
                            const float* __restrict__ gamma, const float* __restrict__ beta) {
    int idx4 = blockIdx.x * 256 + threadIdx.x;
    const int n4 = COUT * DHW_ / 4;
    if (idx4 >= n4) return;
    int c = idx4 / (DHW_ / 4);
    float mean = mi[c], inv = mi[c + COUT];
    float scale = inv * gamma[c];
    float shift = beta[c] - mean * scale;
    float4 x = ((const float4*)out)[idx4];
    x.x = fmaxf(x.x * scale + shift, 0.f);
    x.y = fmaxf(x.y * scale + shift, 0.f);
    x.z = fmaxf(x.z * scale + shift, 0.f);
    x.w = fmaxf(x.w * scale + shift, 0.f);
    ((float4*)out)[idx4] = x;
}

extern "C" void kernel_launch(void* const* d_in, const int* in_sizes, int n_in,
                              void* d_out, int out_size, void* d_ws, size_t ws_size,
                              hipStream_t stream) {
    const float* voxels  = (const float*)d_in[0];   // (V, 16, 32)
    const int*   indices = (const int*)  d_in[1];   // (V, 3) [w,h,d]
    const float* conv_w  = (const float*)d_in[2];   // (32,16,3,3,3)
    const float* conv_b  = (const float*)d_in[3];   // (32,)
    const float* gamma   = (const float*)d_in[4];
    const float* beta    = (const float*)d_in[5];
    float* out = (float*)d_out;

    // workspace layout
    float* feats = (float*)d_ws;                    // V*CIN floats = 2.56 MB
    float* stats = feats + (size_t)V_ * CIN;        // 64 floats
    float* mi    = stats + 2 * COUT;                // 64 floats

    const int n4 = COUT * DHW_ / 4;                 // 16.7M float4

    feats_kernel<<<(V_ * CIN + 255) / 256, 256, 0, stream>>>(voxels, feats);
    fill_kernel<<<(n4 + 255) / 256, 256, 0, stream>>>(out, conv_b, stats);
    scatter_conv_kernel<<<(V_ + NVOX - 1) / NVOX, 256, 0, stream>>>(
        feats, indices, conv_w, out, stats);
    finalize_kernel<<<1, 64, 0, stream>>>(stats, conv_b, mi);
    norm_kernel<<<(n4 + 255) / 256, 256, 0, stream>>>(out, mi, gamma, beta);
}

// Round 2
// 1255.905 us; speedup vs baseline: 1.6848x; 1.6848x over previous
//
#include <hip/hip_runtime.h>

#define D_   32
#define H_   256
#define W_   256
#define HW_  (H_ * W_)
#define DHW_ (D_ * H_ * W_)   // 2097152
#define V_   40000
#define CIN  16
#define COUT 32
#define P_   32
#define EPS_ 1e-5f

// output tile = TD x TH x TW positions; grid of tiles partitions the volume
#define TD 2
#define TH 8
#define TW 32
#define NTX (W_ / TW)          // 8
#define NTY (H_ / TH)          // 32
#define NTZ (D_ / TD)          // 16
#define NT  (NTX * NTY * NTZ)  // 4096 tiles
#define TPOS (TD * TH * TW)    // 512 positions per tile
#define OH 16                  // output channels per block (half of COUT)
#define LIST_CAP 448           // candidate voxel list cap (expected ~264, +11 sigma)

// ---------- K1: feats[v][c] = mean over P of voxels[v][c][:] ----------
__global__ void feats_kernel(const float* __restrict__ vox, float* __restrict__ feats) {
    int idx = blockIdx.x * 256 + threadIdx.x;      // one thread per (v,c)
    if (idx >= V_ * CIN) return;
    const float4* p = (const float4*)(vox + (size_t)idx * P_);
    float s = 0.f;
#pragma unroll
    for (int j = 0; j < P_ / 4; ++j) {
        float4 q = p[j];
        s += q.x + q.y + q.z + q.w;
    }
    feats[idx] = s * (1.0f / (float)P_);
}

// ---------- K2a: count voxels per tile-bin ----------
__global__ void bin_count_kernel(const int* __restrict__ idxs, int* __restrict__ counts) {
    int v = blockIdx.x * 256 + threadIdx.x;
    if (v >= V_) return;
    int w = idxs[3 * v], h = idxs[3 * v + 1], d = idxs[3 * v + 2];
    if ((unsigned)w < W_ && (unsigned)h < H_ && (unsigned)d < D_) {
        int b = (d / TD) * NTY * NTX + (h / TH) * NTX + (w / TW);
        atomicAdd(&counts[b], 1);
    }
}

// ---------- K2b: exclusive prefix over 4096 bins (single block) ----------
__global__ void scan_kernel(const int* __restrict__ counts, int* __restrict__ starts,
                            int* __restrict__ cursor) {
    __shared__ int part[256];
    int t = threadIdx.x;
    int base = t * 16;
    int s = 0;
    for (int j = 0; j < 16; ++j) s += counts[base + j];
    part[t] = s;
    __syncthreads();
    for (int off = 1; off < 256; off <<= 1) {
        int val = part[t];
        int add = (t >= off) ? part[t - off] : 0;
        __syncthreads();
        part[t] = val + add;
        __syncthreads();
    }
    int run = (t > 0) ? part[t - 1] : 0;
    for (int j = 0; j < 16; ++j) {
        starts[base + j] = run;
        cursor[base + j] = run;
        run += counts[base + j];
    }
}

// ---------- K2c: fill bin voxel-id lists ----------
__global__ void bin_fill_kernel(const int* __restrict__ idxs, int* __restrict__ cursor,
                                int* __restrict__ ids) {
    int v = blockIdx.x * 256 + threadIdx.x;
    if (v >= V_) return;
    int w = idxs[3 * v], h = idxs[3 * v + 1], d = idxs[3 * v + 2];
    if ((unsigned)w < W_ && (unsigned)h < H_ && (unsigned)d < D_) {
        int b = (d / TD) * NTY * NTX + (h / TH) * NTX + (w / TW);
        int p = atomicAdd(&cursor[b], 1);
        ids[p] = v;
    }
}

// ---------- K3/K5: tile scatter-conv. PASS=1: BN stats. PASS=2: write output ----------
// block = 256 threads = 16 channels (oo) x 16 voxel slots. One block per (tile, channel-half).
template <int PASS>
__global__ void __launch_bounds__(256, 2) tile_conv_kernel(
    const float* __restrict__ feats, const int* __restrict__ idxs,
    const float* __restrict__ conv_w, const int* __restrict__ starts,
    const int* __restrict__ counts, const int* __restrict__ ids,
    float* __restrict__ stats, const float* __restrict__ mi,
    float* __restrict__ out)
{
    __shared__ float tile[TPOS * 17];        // [pos][oo], stride 17 (conflict-free)
    __shared__ float wsm[27 * CIN * OH];     // [k][i][oo]
    __shared__ int   list[LIST_CAP];
    __shared__ int   nlist;
    __shared__ float wsum[4][16], wsq[4][16];

    int t = threadIdx.x;
    int tile_id = blockIdx.x;
    int half = blockIdx.y;
    int tx = tile_id % NTX, ty = (tile_id / NTX) % NTY, tz = tile_id / (NTX * NTY);
    int w0 = tx * TW, h0 = ty * TH, d0 = tz * TD;
    int obase = half * OH;

    // stage this half's weights: wsm[(k*CIN+i)*OH+oo] = conv_w[((obase+oo)*CIN+i)*27+k]
    for (int j = t; j < 27 * CIN * OH; j += 256) {
        int k = j % 27;
        int i = (j / 27) % CIN;
        int oo = j / (27 * CIN);
        wsm[(k * CIN + i) * OH + oo] = conv_w[((obase + oo) * CIN + i) * 27 + k];
    }
    for (int j = t; j < TPOS * 17; j += 256) tile[j] = 0.f;
    if (t == 0) nlist = 0;
    __syncthreads();

    // build candidate list from 27 neighbor bins, filtered to the tile's halo box
    if (t < 27) {
        int dz = t / 9 - 1, dy = (t / 3) % 3 - 1, dx = t % 3 - 1;
        int nz = tz + dz, ny = ty + dy, nx = tx + dx;
        if ((unsigned)nz < NTZ && (unsigned)ny < NTY && (unsigned)nx < NTX) {
            int b = nz * NTY * NTX + ny * NTX + nx;
            int s = starts[b], c = counts[b];
            for (int j = 0; j < c; ++j) {
                int v = ids[s + j];
                int vw = idxs[3 * v], vh = idxs[3 * v + 1], vd = idxs[3 * v + 2];
                if (vd >= d0 - 1 && vd <= d0 + TD && vh >= h0 - 1 && vh <= h0 + TH &&
                    vw >= w0 - 1 && vw <= w0 + TW) {
                    int p = atomicAdd(&nlist, 1);
                    if (p < LIST_CAP) list[p] = v;
                }
            }
        }
    }
    __syncthreads();
    int nc = min(nlist, LIST_CAP);

    int oo = t & 15;        // channel within half
    int slot = t >> 4;      // 0..15

    // scatter contributions into the LDS tile
    for (int j = slot; j < nc; j += 16) {
        int v = list[j];
        int vw = idxs[3 * v], vh = idxs[3 * v + 1], vd = idxs[3 * v + 2];
        float f[CIN];
        {
            const float4* fp = (const float4*)(feats + (size_t)v * CIN);
            float4 q0 = fp[0], q1 = fp[1], q2 = fp[2], q3 = fp[3];
            f[0] = q0.x;  f[1] = q0.y;  f[2] = q0.z;  f[3] = q0.w;
            f[4] = q1.x;  f[5] = q1.y;  f[6] = q1.z;  f[7] = q1.w;
            f[8] = q2.x;  f[9] = q2.y;  f[10] = q2.z; f[11] = q2.w;
            f[12] = q3.x; f[13] = q3.y; f[14] = q3.z; f[15] = q3.w;
        }
#pragma unroll
        for (int kz = 0; kz < 3; ++kz) {
            int dl = vd + 1 - kz - d0;
            if ((unsigned)dl >= TD) continue;
#pragma unroll
            for (int ky = 0; ky < 3; ++ky) {
                int hl = vh + 1 - ky - h0;
                if ((unsigned)hl >= TH) continue;
#pragma unroll
                for (int kx = 0; kx < 3; ++kx) {
                    int wl = vw + 1 - kx - w0;
                    if ((unsigned)wl >= TW) continue;
                    int k = (kz * 3 + ky) * 3 + kx;
                    const float* wk = &wsm[k * CIN * OH + oo];
                    float acc = 0.f;
#pragma unroll
                    for (int i = 0; i < CIN; ++i) acc += wk[i * OH] * f[i];
                    int pos = (dl * TH + hl) * TW + wl;
                    atomicAdd(&tile[pos * 17 + oo], acc);   // ds_add, fire-and-forget
                }
            }
        }
    }
    __syncthreads();

    if (PASS == 1) {
        // per-channel sum / sum-of-squares over this tile (bias cancels analytically)
        float s1 = 0.f, s2 = 0.f;
        for (int p = slot; p < TPOS; p += 16) {
            float sv = tile[p * 17 + oo];
            s1 += sv;
            s2 += sv * sv;
        }
        s1 += __shfl_xor(s1, 16); s2 += __shfl_xor(s2, 16);
        s1 += __shfl_xor(s1, 32); s2 += __shfl_xor(s2, 32);
        int wave = t >> 6, lane = t & 63;
        if (lane < 16) { wsum[wave][lane] = s1; wsq[wave][lane] = s2; }
        __syncthreads();
        if (t < 16) {
            float a = wsum[0][t] + wsum[1][t] + wsum[2][t] + wsum[3][t];
            float b = wsq[0][t] + wsq[1][t] + wsq[2][t] + wsq[3][t];
            atomicAdd(&stats[obase + t], a);
            atomicAdd(&stats[COUT + obase + t], b);
        }
    } else {
        // y = relu(s*A + B); one coalesced write per position-channel
        int wl = t & 31;
        int r0 = t >> 5;                     // 8 row-threads
        for (int r = r0; r < OH * TD * TH; r += 8) {
            int oo2 = r / (TD * TH);
            int rem = r % (TD * TH);         // dl*TH + hl
            int o = obase + oo2;
            float A = mi[o], B = mi[COUT + o];
            int pos = rem * TW + wl;
            float s = tile[pos * 17 + oo2];
            float y = fmaxf(s * A + B, 0.f);
            int dl = rem / TH, hl = rem % TH;
            out[(size_t)o * DHW_ + (size_t)(d0 + dl) * HW_ + (size_t)(h0 + hl) * W_ +
                (w0 + wl)] = y;
        }
    }
}

// ---------- K4: finalize per-channel scale A and shift B ----------
// x = bias + s; mean = bias + m1; var = m2 - m1^2 (bias cancels).
// y = (x-mean)*gamma*inv + beta = s*A + (-m1*A + beta)
__global__ void finalize_kernel(const float* __restrict__ stats,
                                const float* __restrict__ gamma,
                                const float* __restrict__ beta,
                                float* __restrict__ mi) {
    int t = threadIdx.x;
    if (t < COUT) {
        float n = (float)DHW_;
        float m1 = stats[t] / n;
        float m2 = stats[COUT + t] / n;
        float var = fmaxf(m2 - m1 * m1, 0.f);
        float inv = rsqrtf(var + EPS_);
        float A = gamma[t] * inv;
        mi[t] = A;
        mi[COUT + t] = -m1 * A + beta[t];
    }
}

extern "C" void kernel_launch(void* const* d_in, const int* in_sizes, int n_in,
                              void* d_out, int out_size, void* d_ws, size_t ws_size,
                              hipStream_t stream) {
    const float* voxels  = (const float*)d_in[0];   // (V, 16, 32)
    const int*   indices = (const int*)  d_in[1];   // (V, 3) [w,h,d]
    const float* conv_w  = (const float*)d_in[2];   // (32,16,3,3,3)
    const float* conv_b  = (const float*)d_in[3];   // (32,)  -- cancels analytically
    const float* gamma   = (const float*)d_in[4];
    const float* beta    = (const float*)d_in[5];
    float* out = (float*)d_out;
    (void)conv_b;

    // workspace layout (floats/ints, all 4B)
    float* feats  = (float*)d_ws;                         // V*CIN
    int*   counts = (int*)(feats + (size_t)V_ * CIN);     // NT
    int*   starts = counts + NT;                          // NT
    int*   cursor = starts + NT;                          // NT
    int*   ids    = cursor + NT;                          // V
    float* stats  = (float*)(ids + V_);                   // 2*COUT
    float* mi     = stats + 2 * COUT;                     // 2*COUT

    hipMemsetAsync(counts, 0, NT * sizeof(int), stream);
    hipMemsetAsync(stats, 0, 2 * COUT * sizeof(float), stream);

    feats_kernel<<<(V_ * CIN + 255) / 256, 256, 0, stream>>>(voxels, feats);
    bin_count_kernel<<<(V_ + 255) / 256, 256, 0, stream>>>(indices, counts);
    scan_kernel<<<1, 256, 0, stream>>>(counts, starts, cursor);
    bin_fill_kernel<<<(V_ + 255) / 256, 256, 0, stream>>>(indices, cursor, ids);

    dim3 grid(NT, 2);
    tile_conv_kernel<1><<<grid, 256, 0, stream>>>(feats, indices, conv_w, starts,
                                                  counts, ids, stats, mi, out);
    finalize_kernel<<<1, 64, 0, stream>>>(stats, gamma, beta, mi);
    tile_conv_kernel<2><<<grid, 256, 0, stream>>>(feats, indices, conv_w, starts,
                                                  counts, ids, stats, mi, out);
}

// Round 3
// 752.229 us; speedup vs baseline: 2.8129x; 1.6696x over previous
//
#include <hip/hip_runtime.h>

#define D_   32
#define H_   256
#define W_   256
#define HW_  (H_ * W_)
#define DHW_ (D_ * H_ * W_)   // 2097152
#define V_   40000
#define CIN  16
#define COUT 32
#define P_   32
#define EPS_ 1e-5f

#define TD 2
#define TH 8
#define TW 32
#define NTX (W_ / TW)          // 8
#define NTY (H_ / TH)          // 32
#define NTZ (D_ / TD)          // 16
#define NT  (NTX * NTY * NTZ)  // 4096 tiles
#define TPOS (TD * TH * TW)    // 512
#define OH 16                  // channels per block (half of COUT)
#define TAP_CAP 768            // expected ~257, sigma ~73 (clustered) -> +7 sigma

// ---------- K1: count voxels per tile-bin ----------
__global__ void bin_count_kernel(const int* __restrict__ idxs, int* __restrict__ counts) {
    int v = blockIdx.x * 256 + threadIdx.x;
    if (v >= V_) return;
    int w = idxs[3 * v], h = idxs[3 * v + 1], d = idxs[3 * v + 2];
    if ((unsigned)w < W_ && (unsigned)h < H_ && (unsigned)d < D_) {
        int b = (d / TD) * NTY * NTX + (h / TH) * NTX + (w / TW);
        atomicAdd(&counts[b], 1);
    }
}

// ---------- K2: exclusive prefix over 4096 bins + weight transpose ----------
// wt4[((half*27+k)*4+jj)*16+oo] = float4{ conv_w[o][4jj+i][k] : i=0..3 }, o=half*16+oo
__global__ void scan_kernel(const int* __restrict__ counts, int* __restrict__ starts,
                            int* __restrict__ cursor, const float* __restrict__ conv_w,
                            float4* __restrict__ wt4) {
    __shared__ int part[256];
    int t = threadIdx.x;
    int base = t * 16;
    int s = 0;
    for (int j = 0; j < 16; ++j) s += counts[base + j];
    part[t] = s;
    __syncthreads();
    for (int off = 1; off < 256; off <<= 1) {
        int val = part[t];
        int add = (t >= off) ? part[t - off] : 0;
        __syncthreads();
        part[t] = val + add;
        __syncthreads();
    }
    int run = (t > 0) ? part[t - 1] : 0;
    for (int j = 0; j < 16; ++j) {
        starts[base + j] = run;
        cursor[base + j] = run;
        run += counts[base + j];
    }
    // weight transpose: 3456 float4
    for (int n = t; n < 2 * 27 * 4 * 16; n += 256) {
        int oo = n & 15;
        int jj = (n >> 4) & 3;
        int m  = n >> 6;            // half*27 + k
        int k  = m % 27;
        int half = m / 27;
        int o = half * 16 + oo;
        float4 wv;
        wv.x = conv_w[(o * CIN + 4 * jj + 0) * 27 + k];
        wv.y = conv_w[(o * CIN + 4 * jj + 1) * 27 + k];
        wv.z = conv_w[(o * CIN + 4 * jj + 2) * 27 + k];
        wv.w = conv_w[(o * CIN + 4 * jj + 3) * 27 + k];
        wt4[n] = wv;
    }
}

// ---------- K3: fill bins: packed pos + permutation ----------
__global__ void bin_fill_kernel(const int* __restrict__ idxs, int* __restrict__ cursor,
                                int* __restrict__ pos_packed, int* __restrict__ perm) {
    int v = blockIdx.x * 256 + threadIdx.x;
    if (v >= V_) return;
    int w = idxs[3 * v], h = idxs[3 * v + 1], d = idxs[3 * v + 2];
    if ((unsigned)w < W_ && (unsigned)h < H_ && (unsigned)d < D_) {
        int b = (d / TD) * NTY * NTX + (h / TH) * NTX + (w / TW);
        int p = atomicAdd(&cursor[b], 1);
        pos_packed[p] = (d << 16) | (h << 8) | w;
        perm[v] = p;
    }
}

// ---------- K4: feats (mean over P) written in bin order, float4 granularity ----------
__global__ void featpack_kernel(const float* __restrict__ vox, const int* __restrict__ idxs,
                                const int* __restrict__ perm, float4* __restrict__ feats4) {
    int idx = blockIdx.x * 256 + threadIdx.x;     // (v, chunk-of-4-channels)
    if (idx >= V_ * 4) return;
    int v = idx >> 2, q = idx & 3;
    int w = idxs[3 * v], h = idxs[3 * v + 1], d = idxs[3 * v + 2];
    if (!((unsigned)w < W_ && (unsigned)h < H_ && (unsigned)d < D_)) return;
    int slot = perm[v];
    const float* base = vox + ((size_t)v * CIN + 4 * q) * P_;
    float m[4];
#pragma unroll
    for (int c = 0; c < 4; ++c) {
        const float4* p = (const float4*)(base + c * P_);
        float s = 0.f;
#pragma unroll
        for (int j = 0; j < P_ / 4; ++j) {
            float4 t = p[j];
            s += t.x + t.y + t.z + t.w;
        }
        m[c] = s * (1.0f / (float)P_);
    }
    feats4[slot * 4 + q] = make_float4(m[0], m[1], m[2], m[3]);
}

// ---------- K5: tile conv -> pre-norm output + BN stats (single pass) ----------
// block = 256 = 16 channels x 16 slots; grid = (NT, 2 halves)
__global__ void __launch_bounds__(256, 2) tile_conv_kernel(
    const float4* __restrict__ feats4, const float4* __restrict__ wt4,
    const int* __restrict__ starts, const int* __restrict__ counts,
    const int* __restrict__ pos_packed, float* __restrict__ stats,
    float* __restrict__ out)
{
    __shared__ float  tile[TPOS * 16];     // [pos][oo^(pos&15)] xor-swizzled
    __shared__ float4 wsm4[27 * 4 * 16];   // [(k*4+jj)*16+oo]
    __shared__ int    taps[TAP_CAP];
    __shared__ int    seg_off[28];         // counts then exclusive offsets
    __shared__ int    seg_gs[27];
    __shared__ float  wsum[4][16], wsq[4][16];
    __shared__ int    ntap;

    int t = threadIdx.x;
    int tile_id = blockIdx.x;
    int half = blockIdx.y;
    int tx = tile_id % NTX, ty = (tile_id / NTX) % NTY, tz = tile_id / (NTX * NTY);
    int w0 = tx * TW, h0 = ty * TH, d0 = tz * TD;
    int obase = half * OH;

    // phase A: zero tile, stage weights, fetch neighbor-bin segments
    for (int j = t; j < TPOS * 16 / 4; j += 256) ((float4*)tile)[j] = make_float4(0, 0, 0, 0);
    for (int j = t; j < 27 * 4 * 16; j += 256) wsm4[j] = wt4[half * (27 * 4 * 16) + j];
    if (t < 27) {
        int dz = t / 9 - 1, dy = (t / 3) % 3 - 1, dx = t % 3 - 1;
        int nz = tz + dz, ny = ty + dy, nx = tx + dx;
        int cnt = 0, gs = 0;
        if ((unsigned)nz < NTZ && (unsigned)ny < NTY && (unsigned)nx < NTX) {
            int b = nz * NTY * NTX + ny * NTX + nx;
            gs = starts[b];
            cnt = counts[b];
        }
        seg_gs[t] = gs;
        seg_off[t] = cnt;
    }
    if (t == 0) ntap = 0;
    __syncthreads();
    if (t == 0) {      // tiny serial prefix over 27
        int run = 0;
#pragma unroll
        for (int i = 0; i < 27; ++i) {
            int c = seg_off[i];
            seg_off[i] = run;
            run += c;
        }
        seg_off[27] = run;
    }
    __syncthreads();
    int ncand = seg_off[27];

    // phase B: tap generation (uniform work units)
    for (int j = t; j < ncand; j += 256) {
        int b = 0;
        while (seg_off[b + 1] <= j) ++b;          // <=27 LDS-broadcast steps
        int src = seg_gs[b] + (j - seg_off[b]);
        int pp = pos_packed[src];
        int vw = pp & 255, vh = (pp >> 8) & 255, vd = pp >> 16;
        int dlo = max(vd - 1, d0), dhi = min(vd + 1, d0 + TD - 1);
        int hlo = max(vh - 1, h0), hhi = min(vh + 1, h0 + TH - 1);
        int wlo = max(vw - 1, w0), whi = min(vw + 1, w0 + TW - 1);
        for (int dq = dlo; dq <= dhi; ++dq)
            for (int hq = hlo; hq <= hhi; ++hq)
                for (int wq = wlo; wq <= whi; ++wq) {
                    int k = ((vd - dq + 1) * 3 + (vh - hq + 1)) * 3 + (vw - wq + 1);
                    int pos = ((dq - d0) * TH + (hq - h0)) * TW + (wq - w0);
                    int slot2 = atomicAdd(&ntap, 1);
                    if (slot2 < TAP_CAP) taps[slot2] = (src << 14) | (k << 9) | pos;
                }
    }
    __syncthreads();
    int nt = min(ntap, TAP_CAP);

    // phase C: uniform scatter: each tap = 4 b128 LDS weight reads + 16 FMA + ds_add
    int oo = t & 15;
    int slot = t >> 4;
    for (int j = slot; j < nt; j += 16) {
        unsigned tap = (unsigned)taps[j];
        int pos = tap & 511;
        int k = (tap >> 9) & 31;
        int src = tap >> 14;
        const float4* fp = feats4 + src * 4;      // broadcast across 16 oo lanes
        float4 f0 = fp[0], f1 = fp[1], f2 = fp[2], f3 = fp[3];
        const float4* wp = &wsm4[(k * 4) * 16 + oo];
        float4 q0 = wp[0], q1 = wp[16], q2 = wp[32], q3 = wp[48];
        float acc = q0.x * f0.x + q0.y * f0.y + q0.z * f0.z + q0.w * f0.w
                  + q1.x * f1.x + q1.y * f1.y + q1.z * f1.z + q1.w * f1.w
                  + q2.x * f2.x + q2.y * f2.y + q2.z * f2.z + q2.w * f2.w
                  + q3.x * f3.x + q3.y * f3.y + q3.z * f3.z + q3.w * f3.w;
        atomicAdd(&tile[pos * 16 + (oo ^ (pos & 15))], acc);
    }
    __syncthreads();

    // phase D1: BN partial stats (bias cancels analytically)
    float s1 = 0.f, s2 = 0.f;
    for (int p = slot; p < TPOS; p += 16) {
        float sv = tile[p * 16 + (oo ^ (p & 15))];
        s1 += sv;
        s2 += sv * sv;
    }
    s1 += __shfl_xor(s1, 16); s2 += __shfl_xor(s2, 16);
    s1 += __shfl_xor(s1, 32); s2 += __shfl_xor(s2, 32);
    int wave = t >> 6, lane = t & 63;
    if (lane < 16) { wsum[wave][lane] = s1; wsq[wave][lane] = s2; }

    // phase D2: write pre-norm output, coalesced
    int wl = t & 31;
    for (int r = t >> 5; r < OH * TD * TH; r += 8) {
        int oo2 = r >> 4;          // TD*TH = 16
        int rem = r & 15;
        int pos = rem * TW + wl;
        int dl = rem >> 3, hl = rem & 7;
        out[(size_t)(obase + oo2) * DHW_ + (size_t)(d0 + dl) * HW_ +
            (size_t)(h0 + hl) * W_ + (w0 + wl)] = tile[pos * 16 + (oo2 ^ (pos & 15))];
    }
    __syncthreads();
    if (t < 16) {
        float a = wsum[0][t] + wsum[1][t] + wsum[2][t] + wsum[3][t];
        float b = wsq[0][t] + wsq[1][t] + wsq[2][t] + wsq[3][t];
        atomicAdd(&stats[obase + t], a);
        atomicAdd(&stats[COUT + obase + t], b);
    }
}

// ---------- K6: finalize per-channel scale A and shift B ----------
__global__ void finalize_kernel(const float* __restrict__ stats,
                                const float* __restrict__ gamma,
                                const float* __restrict__ beta,
                                float* __restrict__ mi) {
    int t = threadIdx.x;
    if (t < COUT) {
        float n = (float)DHW_;
        float m1 = stats[t] / n;
        float m2 = stats[COUT + t] / n;
        float var = fmaxf(m2 - m1 * m1, 0.f);
        float inv = rsqrtf(var + EPS_);
        float A = gamma[t] * inv;
        mi[t] = A;
        mi[COUT + t] = -m1 * A + beta[t];
    }
}

// ---------- K7: in-place normalize + affine + ReLU (pure BW) ----------
__global__ void norm_kernel(float* __restrict__ out, const float* __restrict__ mi) {
    int idx4 = blockIdx.x * 256 + threadIdx.x;
    int c = idx4 >> 19;            // DHW_/4 = 2^19
    float A = mi[c], B = mi[COUT + c];
    float4 x = ((const float4*)out)[idx4];
    x.x = fmaxf(x.x * A + B, 0.f);
    x.y = fmaxf(x.y * A + B, 0.f);
    x.z = fmaxf(x.z * A + B, 0.f);
    x.w = fmaxf(x.w * A + B, 0.f);
    ((float4*)out)[idx4] = x;
}

extern "C" void kernel_launch(void* const* d_in, const int* in_sizes, int n_in,
                              void* d_out, int out_size, void* d_ws, size_t ws_size,
                              hipStream_t stream) {
    const float* voxels  = (const float*)d_in[0];
    const int*   indices = (const int*)  d_in[1];
    const float* conv_w  = (const float*)d_in[2];
    const float* gamma   = (const float*)d_in[4];
    const float* beta    = (const float*)d_in[5];
    float* out = (float*)d_out;

    float4* wt4     = (float4*)d_ws;                     // 3456 float4
    float4* feats4  = wt4 + 3456;                        // V*4 float4
    int*    counts  = (int*)(feats4 + (size_t)V_ * 4);   // NT
    int*    starts  = counts + NT;
    int*    cursor  = starts + NT;
    int*    pos_pk  = cursor + NT;                       // V
    int*    perm    = pos_pk + V_;                       // V
    float*  stats   = (float*)(perm + V_);               // 64
    float*  mi      = stats + 2 * COUT;                  // 64

    hipMemsetAsync(counts, 0, NT * sizeof(int), stream);
    hipMemsetAsync(stats, 0, 2 * COUT * sizeof(float), stream);

    bin_count_kernel<<<(V_ + 255) / 256, 256, 0, stream>>>(indices, counts);
    scan_kernel<<<1, 256, 0, stream>>>(counts, starts, cursor, conv_w, wt4);
    bin_fill_kernel<<<(V_ + 255) / 256, 256, 0, stream>>>(indices, cursor, pos_pk, perm);
    featpack_kernel<<<(V_ * 4 + 255) / 256, 256, 0, stream>>>(voxels, indices, perm, feats4);

    dim3 grid(NT, 2);
    tile_conv_kernel<<<grid, 256, 0, stream>>>(feats4, wt4, starts, counts, pos_pk,
                                               stats, out);
    finalize_kernel<<<1, 64, 0, stream>>>(stats, gamma, beta, mi);

    const int n4 = COUT * DHW_ / 4;
    norm_kernel<<<n4 / 256, 256, 0, stream>>>(out, mi);
}